// Round 1
// baseline (140.169 us; speedup 1.0000x reference)
//
#include <hip/hip_runtime.h>
#include <stdint.h>

#define B_ 32
#define S_ 32
#define P_ 2048
#define J_ 32
#define I_ 16

// ---------- bf16 helpers (RNE pack, cheap unpack) ----------
__device__ inline uint32_t bfpack(float a, float b) {
    uint32_t ua = __float_as_uint(a);
    uint32_t ub = __float_as_uint(b);
    ua += 0x7fffu + ((ua >> 16) & 1u);   // round-to-nearest-even
    ub += 0x7fffu + ((ub >> 16) & 1u);
    return (ua >> 16) | (ub & 0xffff0000u);
}
__device__ inline float bflo(uint32_t d) { return __uint_as_float(d << 16); }
__device__ inline float bfhi(uint32_t d) { return __uint_as_float(d & 0xffff0000u); }

__device__ inline float dot4(float4 a, float4 b) {
    return fmaf(a.x, b.x, fmaf(a.y, b.y, fmaf(a.z, b.z, a.w * b.w)));
}

// =====================================================================
// Kernel 1: u_hat[b,s,p,j] = sum_i W[s,p,j,i] * X[b,p,i]
// Stored as bf16 pairs (dword k of a row = j=2k | j=2k+1<<16).
// Thread = (s, p, 4 j's); loops over all 32 b so each W row is read once
// from HBM and reused 32x from registers.
// =====================================================================
__global__ __launch_bounds__(256) void uhat_kernel(
        const float* __restrict__ W, const float* __restrict__ X,
        uint32_t* __restrict__ U) {
    const int tid = threadIdx.x;
    const int jg  = tid & 7;          // 8 groups of 4 j
    const int pl  = tid >> 3;         // 0..31
    const int p   = blockIdx.x * 32 + pl;
    const int s   = blockIdx.y;
    const int j0  = jg * 4;

    // W rows j0..j0+3 (16 floats each) -> 16 float4 in registers (64 VGPR)
    const float4* wp = reinterpret_cast<const float4*>(
        W + (((size_t)s * P_ + p) * J_ + j0) * I_);
    float4 w[16];
    #pragma unroll
    for (int q = 0; q < 16; ++q) w[q] = wp[q];

    const float4* xp = reinterpret_cast<const float4*>(X) + (size_t)p * 4;

    #pragma unroll 2
    for (int b = 0; b < B_; ++b) {
        const float4* xb = xp + (size_t)b * (P_ * 4);
        float4 x0 = xb[0], x1 = xb[1], x2 = xb[2], x3 = xb[3];
        float a0 = dot4(w[0],  x0) + dot4(w[1],  x1) + dot4(w[2],  x2) + dot4(w[3],  x3);
        float a1 = dot4(w[4],  x0) + dot4(w[5],  x1) + dot4(w[6],  x2) + dot4(w[7],  x3);
        float a2 = dot4(w[8],  x0) + dot4(w[9],  x1) + dot4(w[10], x2) + dot4(w[11], x3);
        float a3 = dot4(w[12], x0) + dot4(w[13], x1) + dot4(w[14], x2) + dot4(w[15], x3);
        uint2 d;
        d.x = bfpack(a0, a1);
        d.y = bfpack(a2, a3);
        *reinterpret_cast<uint2*>(
            U + (((size_t)b * S_ + s) * P_ + p) * (J_ / 2) + (j0 >> 1)) = d;
    }
}

// ---------- split-butterfly wave reduction of a 32-vector ----------
// After all levels + final xor-1 add, lane holds full 64-lane sum of
// component j = (lane >> 1).
template <int MASK, int HALF>
__device__ inline void red_level(float* red, int lane) {
    const bool hi = (lane & MASK) != 0;
    #pragma unroll
    for (int k = 0; k < HALF; ++k) {
        float send = hi ? red[k] : red[k + HALF];
        float recv = __shfl_xor(send, MASK, 64);
        red[k] = (hi ? red[k + HALF] : red[k]) + recv;
    }
}

// =====================================================================
// Kernel 2: dynamic routing. One 1024-thread block per (b,s).
// Thread owns rows p0=2*tid, p1=2*tid+1 of u_hat (bf16-packed, 32 VGPR).
// All 3 iterations run with u_hat in registers (single HBM read).
// =====================================================================
__global__ __launch_bounds__(1024) void routing_kernel(
        const uint32_t* __restrict__ U, float* __restrict__ out) {
    const int tid  = threadIdx.x;
    const int lane = tid & 63;
    const int wid  = tid >> 6;            // 0..15
    const int bs   = blockIdx.x;          // b*S_ + s

    __shared__ float sred[16 * 32];       // per-wave 32-vector partials
    __shared__ __align__(16) float vlds[32];
    __shared__ float scal[32];            // [0..15] max partials, [16..31] sum partials

    // load my 2 rows: 32 dwords = 128B contiguous
    const uint32_t* ub = U + (size_t)bs * P_ * (J_ / 2) + (size_t)tid * 32;
    uint32_t a[32];
    #pragma unroll
    for (int k = 0; k < 8; ++k) {
        uint4 t = reinterpret_cast<const uint4*>(ub)[k];
        a[k * 4 + 0] = t.x; a[k * 4 + 1] = t.y;
        a[k * 4 + 2] = t.z; a[k * 4 + 3] = t.w;
    }
    // a[0..15] = row p0 (j pairs), a[16..31] = row p1

    float bp0 = 0.0f, bp1 = 0.0f;         // routing logits for my two p's

    for (int it = 0; it < 3; ++it) {
        // ---- c = softmax(b) over p ----
        float c0, c1;
        if (it == 0) {
            c0 = c1 = 1.0f / 2048.0f;     // softmax of zeros, exact
        } else {
            float m = fmaxf(bp0, bp1);
            #pragma unroll
            for (int msk = 32; msk >= 1; msk >>= 1)
                m = fmaxf(m, __shfl_xor(m, msk, 64));
            if (lane == 0) scal[wid] = m;
            __syncthreads();
            m = scal[0];
            #pragma unroll
            for (int w2 = 1; w2 < 16; ++w2) m = fmaxf(m, scal[w2]);
            float e0 = __expf(bp0 - m);
            float e1 = __expf(bp1 - m);
            float zs = e0 + e1;
            #pragma unroll
            for (int msk = 32; msk >= 1; msk >>= 1)
                zs += __shfl_xor(zs, msk, 64);
            if (lane == 0) scal[16 + wid] = zs;
            __syncthreads();
            float Z = 0.0f;
            #pragma unroll
            for (int w2 = 0; w2 < 16; ++w2) Z += scal[16 + w2];
            float invZ = 1.0f / Z;
            c0 = e0 * invZ;
            c1 = e1 * invZ;
        }

        // ---- per-thread partial s_j = c0*u[p0][j] + c1*u[p1][j] ----
        float red[32];
        #pragma unroll
        for (int k = 0; k < 16; ++k) {
            uint32_t d0 = a[k], d1 = a[16 + k];
            red[2 * k]     = fmaf(c0, bflo(d0), c1 * bflo(d1));
            red[2 * k + 1] = fmaf(c0, bfhi(d0), c1 * bfhi(d1));
        }
        // ---- wave reduce-scatter (31 shfl total) ----
        red_level<32, 16>(red, lane);
        red_level<16, 8>(red, lane);
        red_level<8, 4>(red, lane);
        red_level<4, 2>(red, lane);
        red_level<2, 1>(red, lane);
        red[0] += __shfl_xor(red[0], 1, 64);   // lane holds s_{lane>>1} wave-sum
        if ((lane & 1) == 0) sred[wid * 32 + (lane >> 1)] = red[0];
        __syncthreads();

        // ---- cross-wave finalize + squash (first 32 threads) ----
        if (tid < 32) {
            float s = 0.0f;
            #pragma unroll
            for (int w2 = 0; w2 < 16; ++w2) s += sred[w2 * 32 + tid];
            float sq = s * s;
            #pragma unroll
            for (int msk = 16; msk >= 1; msk >>= 1)
                sq += __shfl_xor(sq, msk, 64);
            float n = sqrtf(sq);
            float scale = sq / ((1.0f + sq) * (n + 1e-7f));
            float v = s * scale;
            vlds[tid] = v;
            if (it == 2) out[(size_t)bs * J_ + tid] = v;
        }
        __syncthreads();

        // ---- agreement + logit update (not needed after last iter) ----
        if (it < 2) {
            const float2* vl2 = reinterpret_cast<const float2*>(vlds);
            float ag0 = 0.0f, ag1 = 0.0f;
            #pragma unroll
            for (int k = 0; k < 16; ++k) {
                float2 vk = vl2[k];               // v[2k], v[2k+1] (LDS broadcast)
                uint32_t d0 = a[k], d1 = a[16 + k];
                ag0 = fmaf(vk.x, bflo(d0), ag0);
                ag0 = fmaf(vk.y, bfhi(d0), ag0);
                ag1 = fmaf(vk.x, bflo(d1), ag1);
                ag1 = fmaf(vk.y, bfhi(d1), ag1);
            }
            bp0 += ag0;
            bp1 += ag1;
        }
    }
}

extern "C" void kernel_launch(void* const* d_in, const int* in_sizes, int n_in,
                              void* d_out, int out_size, void* d_ws, size_t ws_size,
                              hipStream_t stream) {
    (void)in_sizes; (void)n_in; (void)out_size;
    const float* X = (const float*)d_in[0];        // [B,P,I] fp32
    const float* W = (const float*)d_in[1];        // [S,P,J,I] fp32
    float* out     = (float*)d_out;                // [B,S,J] fp32
    uint32_t* U    = (uint32_t*)d_ws;              // bf16 u_hat [B,S,P,J/2 dwords]

    const size_t need = (size_t)B_ * S_ * P_ * J_ * 2;  // 128 MiB
    if (ws_size < need) return;  // cannot run without scratch

    dim3 g1(P_ / 32, S_);
    uhat_kernel<<<g1, 256, 0, stream>>>(W, X, U);
    routing_kernel<<<B_ * S_, 1024, 0, stream>>>(U, out);
}